// Round 8
// baseline (538.673 us; speedup 1.0000x reference)
//
#include <hip/hip_runtime.h>

#define NN 50000
#define NE 1600000
#define CLAMP_V 5.0f
#define NXCC 8

typedef __attribute__((ext_vector_type(4))) short bf16x4;
typedef __attribute__((ext_vector_type(4))) float f32x4;

static __device__ __forceinline__ short f2bf(float x) {
    unsigned u = __builtin_bit_cast(unsigned, x);
    u += 0x7FFF + ((u >> 16) & 1);   // round-to-nearest-even
    return (short)(u >> 16);
}

__global__ __launch_bounds__(256) void proj_kernel(
    const float* __restrict__ x,
    const float* __restrict__ WQ, const float* __restrict__ bQ,
    const float* __restrict__ WK, const float* __restrict__ WVw,
    float* __restrict__ Q, float* __restrict__ K, float* __restrict__ V)
{
    __shared__ float sWQ[4096], sWK[4096], sWV[4096];
    for (int i = threadIdx.x; i < 4096; i += 256) {
        sWQ[i] = WQ[i]; sWK[i] = WK[i]; sWV[i] = WVw[i];
    }
    __syncthreads();
    const int col = threadIdx.x & 63;
    const int nl  = threadIdx.x >> 6;
    const float bq = bQ[col];
    for (int node = blockIdx.x * 4 + nl; node < NN; node += gridDim.x * 4) {
        const float* xr = x + (size_t)node * 64;
        float aq = 0.f, ak = 0.f, av = 0.f;
        #pragma unroll
        for (int j = 0; j < 64; ++j) {
            float xv = xr[j];
            aq = fmaf(xv, sWQ[j*64+col], aq);
            ak = fmaf(xv, sWK[j*64+col], ak);
            av = fmaf(xv, sWV[j*64+col], av);
        }
        Q[(size_t)node*64+col] = aq + bq;
        K[(size_t)node*64+col] = ak;
        V[(size_t)node*64+col] = av;
    }
}

// Fused edge pass. PART=true: per-XCD partial Num/den buffers updated with
// workgroup-scope atomics (RMW stays in the local L2; only one XCD ever
// touches a given partial buffer, so no cross-XCD coherence is needed).
template<bool PART>
__global__ __launch_bounds__(256) void edge_fused_kernel(
    const float* __restrict__ edge_attr,
    const float* __restrict__ WE1, const float* __restrict__ bE1,
    const int* __restrict__ ei,
    const float* __restrict__ Q, const float* __restrict__ K,
    const float* __restrict__ V,
    float* __restrict__ wE, float* __restrict__ den, float* __restrict__ Num)
{
    __shared__ float Elds[4][16 * 64];   // [wave][edge][col]: E tile, then P in-place
    const int tid  = threadIdx.x;
    const int wv   = tid >> 6;
    const int lane = tid & 63;
    const int g    = lane >> 4;      // k-group (MFMA) / edge-in-quad (scoring)
    const int rowl = lane & 15;      // A-row (MFMA) / col-quad (scoring)

    unsigned xcc = 0;
    if constexpr (PART) {
        asm volatile("s_getreg_b32 %0, hwreg(HW_REG_XCC_ID)" : "=s"(xcc));
        xcc &= (NXCC - 1);
    }
    float* __restrict__ nump = Num + (size_t)xcc * (NN * 64);
    float* __restrict__ denp = den + (size_t)xcc * (NN * 8);

    // B fragments of WE1 (bf16) + bias. B[k=(ks*16 + g*4 + j)][col]
    bf16x4 bF[4][4];
    float  bias[4];
    #pragma unroll
    for (int cb = 0; cb < 4; ++cb) {
        const int col = rowl + 16 * cb;
        bias[cb] = bE1[col];
        #pragma unroll
        for (int ks = 0; ks < 4; ++ks) {
            bf16x4 t;
            #pragma unroll
            for (int j = 0; j < 4; ++j)
                t[j] = f2bf(WE1[(ks * 16 + g * 4 + j) * 64 + col]);
            bF[cb][ks] = t;
        }
    }

    const float inv_sqrt8 = 0.35355339059327373f;

    for (int tile = blockIdx.x; tile < (NE / 64); tile += gridDim.x) {
        const int eBase = tile * 64 + wv * 16;

        const int srcv = ei[eBase + rowl];
        const int dstv = ei[NE + eBase + rowl];

        // A fragments: edge_attr[eBase+rowl][ks*16 + g*4 + j] (nontemporal)
        bf16x4 aF[4];
        const float* ar = edge_attr + (size_t)(eBase + rowl) * 64 + g * 4;
        #pragma unroll
        for (int ks = 0; ks < 4; ++ks) {
            f32x4 v = __builtin_nontemporal_load(
                reinterpret_cast<const f32x4*>(ar + ks * 16));
            bf16x4 t;
            #pragma unroll
            for (int j = 0; j < 4; ++j) t[j] = f2bf(v[j]);
            aF[ks] = t;
        }

        f32x4 acc[4];
        #pragma unroll
        for (int cb = 0; cb < 4; ++cb) {
            acc[cb][0] = bias[cb]; acc[cb][1] = bias[cb];
            acc[cb][2] = bias[cb]; acc[cb][3] = bias[cb];
        }
        #pragma unroll
        for (int cb = 0; cb < 4; ++cb)
            #pragma unroll
            for (int ks = 0; ks < 4; ++ks)
                acc[cb] = __builtin_amdgcn_mfma_f32_16x16x16bf16_1k(
                    aF[ks], bF[cb][ks], acc[cb], 0, 0, 0);

        // D layout: row=(lane>>4)*4+r, col=(lane&15)+16*cb  -> LDS transpose
        #pragma unroll
        for (int cb = 0; cb < 4; ++cb)
            #pragma unroll
            for (int r = 0; r < 4; ++r)
                Elds[wv][(g * 4 + r) * 64 + rowl + 16 * cb] = acc[cb][r];

        // Scoring: 4 edges in parallel, float4 per lane; P overwrites E in LDS
        const int h = rowl >> 1;
        #pragma unroll
        for (int qi = 0; qi < 4; ++qi) {
            const int el  = qi * 4 + g;
            const int e   = eBase + el;
            const int src = __shfl(srcv, el);
            const int dst = __shfl(dstv, el);
            const f32x4 Kv = *reinterpret_cast<const f32x4*>(K + (size_t)src * 64 + rowl * 4);
            const f32x4 Qv = *reinterpret_cast<const f32x4*>(Q + (size_t)dst * 64 + rowl * 4);
            const f32x4 Vv = *reinterpret_cast<const f32x4*>(V + (size_t)src * 64 + rowl * 4);
            f32x4* eslot = reinterpret_cast<f32x4*>(&Elds[wv][el * 64 + rowl * 4]);
            const f32x4 El = *eslot;
            f32x4 sc;
            #pragma unroll
            for (int j = 0; j < 4; ++j) sc[j] = Kv[j] * Qv[j] * El[j];
            __builtin_nontemporal_store(sc,
                reinterpret_cast<f32x4*>(wE + (size_t)e * 64 + rowl * 4));
            float ss = sc[0] + sc[1] + sc[2] + sc[3];
            ss += __shfl_xor(ss, 1);
            float s = fminf(fmaxf(ss * inv_sqrt8, -CLAMP_V), CLAMP_V);
            float ex = __expf(s);
            if ((rowl & 1) == 0) {
                if constexpr (PART)
                    __hip_atomic_fetch_add(&denp[dst * 8 + h], ex,
                                           __ATOMIC_RELAXED, __HIP_MEMORY_SCOPE_WORKGROUP);
                else
                    atomicAdd(&denp[dst * 8 + h], ex);
            }
            f32x4 t;
            #pragma unroll
            for (int j = 0; j < 4; ++j) t[j] = ex * (Vv[j] + sc[j]);
            *eslot = t;
        }

        // Atomic phase: one 256B-contiguous atomic instruction per edge
        #pragma unroll
        for (int el = 0; el < 16; ++el) {
            const int dst = __shfl(dstv, el);
            const float pv = Elds[wv][el * 64 + lane];
            if constexpr (PART)
                __hip_atomic_fetch_add(&nump[(size_t)dst * 64 + lane], pv,
                                       __ATOMIC_RELAXED, __HIP_MEMORY_SCOPE_WORKGROUP);
            else
                atomicAdd(&nump[(size_t)dst * 64 + lane], pv);
        }
    }
}

// PART path: sum 8 partials + divide
__global__ __launch_bounds__(256) void reduce_kernel(
    const float* __restrict__ Num_p, const float* __restrict__ den_p,
    float* __restrict__ wV)
{
    const int i = blockIdx.x * 256 + threadIdx.x;   // one float4 per thread
    if (i >= NN * 16) return;
    const int c4 = i & 15;
    const int n  = i >> 4;
    const int h  = c4 >> 1;
    f32x4 s; s[0] = s[1] = s[2] = s[3] = 0.f;
    float d = 0.f;
    #pragma unroll
    for (int x = 0; x < NXCC; ++x) {
        const f32x4 v = reinterpret_cast<const f32x4*>(Num_p)[(size_t)x * (NN * 16) + i];
        s[0] += v[0]; s[1] += v[1]; s[2] += v[2]; s[3] += v[3];
        d += den_p[(size_t)x * (NN * 8) + n * 8 + h];
    }
    const float r = 1.f / (d + 1e-16f);
    s[0] *= r; s[1] *= r; s[2] *= r; s[3] *= r;
    reinterpret_cast<f32x4*>(wV)[i] = s;
}

// fallback finalize (single-buffer path)
__global__ __launch_bounds__(256) void finalize_kernel(
    const float* __restrict__ Num, const float* __restrict__ den,
    float* __restrict__ wV)
{
    const int i = blockIdx.x * 256 + threadIdx.x;
    if (i >= NN * 16) return;
    const int c4 = i & 15;
    const int n  = i >> 4;
    const int h  = c4 >> 1;
    const float d = den[n * 8 + h] + 1e-16f;
    f32x4 v = reinterpret_cast<const f32x4*>(Num)[i];
    v[0] /= d; v[1] /= d; v[2] /= d; v[3] /= d;
    reinterpret_cast<f32x4*>(wV)[i] = v;
}

extern "C" void kernel_launch(void* const* d_in, const int* in_sizes, int n_in,
                              void* d_out, int out_size, void* d_ws, size_t ws_size,
                              hipStream_t stream) {
    const float* x         = (const float*)d_in[0];
    const float* edge_attr = (const float*)d_in[1];
    const float* WQ        = (const float*)d_in[2];
    const float* bQ        = (const float*)d_in[3];
    const float* WK        = (const float*)d_in[4];
    const float* WVw       = (const float*)d_in[5];
    const float* WE1       = (const float*)d_in[6];
    const float* bE1       = (const float*)d_in[7];
    const int*   ei        = (const int*)d_in[8];

    float* out = (float*)d_out;
    float* wV = out;                          // [NN, 64]
    float* wE = out + (size_t)NN * 64;        // [NE, 64]

    float* Q = (float*)d_ws;                  // [NN,64]
    float* K = Q + (size_t)NN * 64;           // [NN,64]
    float* V = K + (size_t)NN * 64;           // [NN,64]

    const size_t needPart =
        ((size_t)NN * 64 * 3 + (size_t)NN * 8 * NXCC + (size_t)NN * 64 * NXCC)
        * sizeof(float);
    const bool part = ws_size >= needPart;

    if (part) {
        float* den_p = V + (size_t)NN * 64;                 // [NXCC][NN,8]
        float* Num_p = den_p + (size_t)NN * 8 * NXCC;       // [NXCC][NN,64]
        hipMemsetAsync(den_p, 0,
                       ((size_t)NN * 8 + (size_t)NN * 64) * NXCC * sizeof(float),
                       stream);
        proj_kernel<<<2048, 256, 0, stream>>>(x, WQ, bQ, WK, WVw, Q, K, V);
        edge_fused_kernel<true><<<2048, 256, 0, stream>>>(
            edge_attr, WE1, bE1, ei, Q, K, V, wE, den_p, Num_p);
        reduce_kernel<<<(NN * 16 + 255) / 256, 256, 0, stream>>>(Num_p, den_p, wV);
    } else {
        float* den = V + (size_t)NN * 64;        // [NN,8]
        float* Num = den + (size_t)NN * 8;       // [NN,64]
        hipMemsetAsync(den, 0, (size_t)NN * 8  * sizeof(float), stream);
        hipMemsetAsync(Num, 0, (size_t)NN * 64 * sizeof(float), stream);
        proj_kernel<<<2048, 256, 0, stream>>>(x, WQ, bQ, WK, WVw, Q, K, V);
        edge_fused_kernel<false><<<2048, 256, 0, stream>>>(
            edge_attr, WE1, bE1, ei, Q, K, V, wE, den, Num);
        finalize_kernel<<<(NN * 16 + 255) / 256, 256, 0, stream>>>(Num, den, wV);
    }
}

// Round 9
// 535.510 us; speedup vs baseline: 1.0059x; 1.0059x over previous
//
#include <hip/hip_runtime.h>

#define NN 50000
#define NE 1600000
#define CLAMP_V 5.0f
#define NB 2048                    // histogram/scatter blocks
#define CH ((NE + NB - 1) / NB)    // edges per block chunk
#define BSHIFT 11                  // 2048 nodes per bucket
#define NBUCK ((NN + (1 << BSHIFT) - 1) >> BSHIFT)   // 25

typedef __attribute__((ext_vector_type(4))) short bf16x4;
typedef __attribute__((ext_vector_type(4))) float f32x4;

static __device__ __forceinline__ short f2bf(float x) {
    unsigned u = __builtin_bit_cast(unsigned, x);
    u += 0x7FFF + ((u >> 16) & 1);   // round-to-nearest-even
    return (short)(u >> 16);
}

__global__ __launch_bounds__(256) void proj_kernel(
    const float* __restrict__ x,
    const float* __restrict__ WQ, const float* __restrict__ bQ,
    const float* __restrict__ WK, const float* __restrict__ WVw,
    float* __restrict__ Q, float* __restrict__ K, float* __restrict__ V)
{
    __shared__ float sWQ[4096], sWK[4096], sWV[4096];
    for (int i = threadIdx.x; i < 4096; i += 256) {
        sWQ[i] = WQ[i]; sWK[i] = WK[i]; sWV[i] = WVw[i];
    }
    __syncthreads();
    const int col = threadIdx.x & 63;
    const int nl  = threadIdx.x >> 6;
    const float bq = bQ[col];
    for (int node = blockIdx.x * 4 + nl; node < NN; node += gridDim.x * 4) {
        const float* xr = x + (size_t)node * 64;
        float aq = 0.f, ak = 0.f, av = 0.f;
        #pragma unroll
        for (int j = 0; j < 64; ++j) {
            float xv = xr[j];
            aq = fmaf(xv, sWQ[j*64+col], aq);
            ak = fmaf(xv, sWK[j*64+col], ak);
            av = fmaf(xv, sWV[j*64+col], av);
        }
        Q[(size_t)node*64+col] = aq + bq;
        K[(size_t)node*64+col] = ak;
        V[(size_t)node*64+col] = av;
    }
}

// Per-block bucket histogram over a contiguous edge chunk.
__global__ __launch_bounds__(256) void hist_kernel(
    const int* __restrict__ ei, int* __restrict__ blockHist)
{
    __shared__ int h[32];
    if (threadIdx.x < 32) h[threadIdx.x] = 0;
    __syncthreads();
    const int b  = blockIdx.x;
    const int e0 = b * CH;
    const int e1 = (e0 + CH < NE) ? e0 + CH : NE;
    for (int e = e0 + threadIdx.x; e < e1; e += 256)
        atomicAdd(&h[ei[NE + e] >> BSHIFT], 1);
    __syncthreads();
    if (threadIdx.x < NBUCK) blockHist[b * 32 + threadIdx.x] = h[threadIdx.x];
}

// One wave per bucket: exclusive scan over the 2048 block counts (in place),
// emit bucket total.
__global__ __launch_bounds__(64) void scanA_kernel(
    int* __restrict__ blockHist, int* __restrict__ bucketTotal)
{
    const int k    = blockIdx.x;          // bucket
    const int lane = threadIdx.x;
    int running = 0;
    for (int c = 0; c < NB; c += 64) {
        int v = blockHist[(c + lane) * 32 + k];
        int incl = v;
        #pragma unroll
        for (int d = 1; d < 64; d <<= 1) {
            int t = __shfl_up(incl, d);
            if (lane >= d) incl += t;
        }
        blockHist[(c + lane) * 32 + k] = running + (incl - v);   // exclusive
        running += __shfl(incl, 63);
    }
    if (lane == 0) bucketTotal[k] = running;
}

__global__ void scanB_kernel(const int* __restrict__ bucketTotal,
                             int* __restrict__ bucketStart)
{
    int acc = 0;
    for (int k = 0; k < NBUCK; ++k) { bucketStart[k] = acc; acc += bucketTotal[k]; }
}

// Scatter edges into dst-bucket order (same chunk partition as hist).
__global__ __launch_bounds__(256) void scatter_kernel(
    const int* __restrict__ ei, const int* __restrict__ blockHist,
    const int* __restrict__ bucketStart,
    int* __restrict__ sortedE, int2* __restrict__ sortedSD)
{
    __shared__ int cur[32];
    const int b = blockIdx.x;
    if (threadIdx.x < NBUCK)
        cur[threadIdx.x] = bucketStart[threadIdx.x] + blockHist[b * 32 + threadIdx.x];
    __syncthreads();
    const int e0 = b * CH;
    const int e1 = (e0 + CH < NE) ? e0 + CH : NE;
    for (int e = e0 + threadIdx.x; e < e1; e += 256) {
        const int src = ei[e], dst = ei[NE + e];
        const int pos = atomicAdd(&cur[dst >> BSHIFT], 1);
        sortedE[pos]  = e;
        sortedSD[pos] = make_int2(src, dst);
    }
}

// Fused edge pass over dst-binned edges. E = edge_attr@WE1+bE1 (MFMA),
// sc = K[src]*Q[dst]*E -> wE (scattered by original edge id, nontemporal),
// ex = exp(clamp(sum_head/sqrt8)); den[dst,h] += ex;
// Num[dst,:] += ex*(V[src]+sc) as one 256B-contiguous atomic per edge.
// dst-binning keeps the atomic target window cache-resident.
__global__ __launch_bounds__(256) void edge_fused_kernel(
    const float* __restrict__ edge_attr,
    const float* __restrict__ WE1, const float* __restrict__ bE1,
    const int* __restrict__ sortedE, const int2* __restrict__ sortedSD,
    const float* __restrict__ Q, const float* __restrict__ K,
    const float* __restrict__ V,
    float* __restrict__ wE, float* __restrict__ den, float* __restrict__ Num)
{
    __shared__ float Elds[4][16 * 64];   // [wave][edge][col]: E tile, then P in-place
    const int tid  = threadIdx.x;
    const int wv   = tid >> 6;
    const int lane = tid & 63;
    const int g    = lane >> 4;      // k-group (MFMA) / edge-in-quad (scoring)
    const int rowl = lane & 15;      // A-row (MFMA) / col-quad (scoring)

    // B fragments of WE1 (bf16) + bias. B[k=(ks*16 + g*4 + j)][col]
    bf16x4 bF[4][4];
    float  bias[4];
    #pragma unroll
    for (int cb = 0; cb < 4; ++cb) {
        const int col = rowl + 16 * cb;
        bias[cb] = bE1[col];
        #pragma unroll
        for (int ks = 0; ks < 4; ++ks) {
            bf16x4 t;
            #pragma unroll
            for (int j = 0; j < 4; ++j)
                t[j] = f2bf(WE1[(ks * 16 + g * 4 + j) * 64 + col]);
            bF[cb][ks] = t;
        }
    }

    const float inv_sqrt8 = 0.35355339059327373f;

    for (int tile = blockIdx.x; tile < (NE / 64); tile += gridDim.x) {
        const int pBase = tile * 64 + wv * 16;   // position in sorted order

        const int2 sdv  = sortedSD[pBase + rowl];  // lane rowl: edge rowl's (src,dst)
        const int  eidv = sortedE[pBase + rowl];
        const int  srcv = sdv.x, dstv = sdv.y;

        // A fragments: edge_attr[eid][ks*16 + g*4 + j] (nontemporal gather)
        bf16x4 aF[4];
        const float* ar = edge_attr + (size_t)eidv * 64 + g * 4;
        #pragma unroll
        for (int ks = 0; ks < 4; ++ks) {
            f32x4 v = __builtin_nontemporal_load(
                reinterpret_cast<const f32x4*>(ar + ks * 16));
            bf16x4 t;
            #pragma unroll
            for (int j = 0; j < 4; ++j) t[j] = f2bf(v[j]);
            aF[ks] = t;
        }

        f32x4 acc[4];
        #pragma unroll
        for (int cb = 0; cb < 4; ++cb) {
            acc[cb][0] = bias[cb]; acc[cb][1] = bias[cb];
            acc[cb][2] = bias[cb]; acc[cb][3] = bias[cb];
        }
        #pragma unroll
        for (int cb = 0; cb < 4; ++cb)
            #pragma unroll
            for (int ks = 0; ks < 4; ++ks)
                acc[cb] = __builtin_amdgcn_mfma_f32_16x16x16bf16_1k(
                    aF[ks], bF[cb][ks], acc[cb], 0, 0, 0);

        // D layout: row=(lane>>4)*4+r, col=(lane&15)+16*cb  -> LDS transpose
        #pragma unroll
        for (int cb = 0; cb < 4; ++cb)
            #pragma unroll
            for (int r = 0; r < 4; ++r)
                Elds[wv][(g * 4 + r) * 64 + rowl + 16 * cb] = acc[cb][r];

        // Scoring: 4 edges in parallel, float4 per lane; P overwrites E in LDS
        const int h = rowl >> 1;
        #pragma unroll
        for (int qi = 0; qi < 4; ++qi) {
            const int el  = qi * 4 + g;
            const int eid = __shfl(eidv, el);
            const int src = __shfl(srcv, el);
            const int dst = __shfl(dstv, el);
            const f32x4 Kv = *reinterpret_cast<const f32x4*>(K + (size_t)src * 64 + rowl * 4);
            const f32x4 Qv = *reinterpret_cast<const f32x4*>(Q + (size_t)dst * 64 + rowl * 4);
            const f32x4 Vv = *reinterpret_cast<const f32x4*>(V + (size_t)src * 64 + rowl * 4);
            f32x4* eslot = reinterpret_cast<f32x4*>(&Elds[wv][el * 64 + rowl * 4]);
            const f32x4 El = *eslot;
            f32x4 sc;
            #pragma unroll
            for (int j = 0; j < 4; ++j) sc[j] = Kv[j] * Qv[j] * El[j];
            __builtin_nontemporal_store(sc,
                reinterpret_cast<f32x4*>(wE + (size_t)eid * 64 + rowl * 4));
            float ss = sc[0] + sc[1] + sc[2] + sc[3];
            ss += __shfl_xor(ss, 1);
            float s = fminf(fmaxf(ss * inv_sqrt8, -CLAMP_V), CLAMP_V);
            float ex = __expf(s);
            if ((rowl & 1) == 0)
                atomicAdd(&den[dst * 8 + h], ex);
            f32x4 t;
            #pragma unroll
            for (int j = 0; j < 4; ++j) t[j] = ex * (Vv[j] + sc[j]);
            *eslot = t;
        }

        // Atomic phase: one 256B-contiguous atomic instruction per edge
        #pragma unroll
        for (int el = 0; el < 16; ++el) {
            const int dst = __shfl(dstv, el);
            atomicAdd(&Num[(size_t)dst * 64 + lane], Elds[wv][el * 64 + lane]);
        }
    }
}

__global__ __launch_bounds__(256) void finalize_kernel(
    const float* __restrict__ Num, const float* __restrict__ den,
    float* __restrict__ wV)
{
    const int i = blockIdx.x * 256 + threadIdx.x;   // one float4 per thread
    if (i >= NN * 16) return;
    const int c4 = i & 15;
    const int n  = i >> 4;
    const int h  = c4 >> 1;
    const float d = den[n * 8 + h] + 1e-16f;
    f32x4 v = reinterpret_cast<const f32x4*>(Num)[i];
    v[0] /= d; v[1] /= d; v[2] /= d; v[3] /= d;
    reinterpret_cast<f32x4*>(wV)[i] = v;
}

extern "C" void kernel_launch(void* const* d_in, const int* in_sizes, int n_in,
                              void* d_out, int out_size, void* d_ws, size_t ws_size,
                              hipStream_t stream) {
    const float* x         = (const float*)d_in[0];
    const float* edge_attr = (const float*)d_in[1];
    const float* WQ        = (const float*)d_in[2];
    const float* bQ        = (const float*)d_in[3];
    const float* WK        = (const float*)d_in[4];
    const float* WVw       = (const float*)d_in[5];
    const float* WE1       = (const float*)d_in[6];
    const float* bE1       = (const float*)d_in[7];
    const int*   ei        = (const int*)d_in[8];

    float* out = (float*)d_out;
    float* wV = out;                          // [NN, 64]
    float* wE = out + (size_t)NN * 64;        // [NE, 64]

    float* Q           = (float*)d_ws;                 // [NN,64]
    float* K           = Q + (size_t)NN * 64;          // [NN,64]
    float* V           = K + (size_t)NN * 64;          // [NN,64]
    float* den         = V + (size_t)NN * 64;          // [NN,8]
    float* Num         = den + (size_t)NN * 8;         // [NN,64]
    int*   blockHist   = (int*)(Num + (size_t)NN * 64);// [NB,32]
    int*   bucketTotal = blockHist + NB * 32;          // [32]
    int*   bucketStart = bucketTotal + 32;             // [32]
    int*   sortedE     = bucketStart + 32;             // [NE]
    int2*  sortedSD    = (int2*)(sortedE + NE);        // [NE]

    hipMemsetAsync(den, 0, (size_t)NN * (8 + 64) * sizeof(float), stream);

    hist_kernel<<<NB, 256, 0, stream>>>(ei, blockHist);
    scanA_kernel<<<NBUCK, 64, 0, stream>>>(blockHist, bucketTotal);
    scanB_kernel<<<1, 1, 0, stream>>>(bucketTotal, bucketStart);
    scatter_kernel<<<NB, 256, 0, stream>>>(ei, blockHist, bucketStart,
                                           sortedE, sortedSD);
    proj_kernel<<<2048, 256, 0, stream>>>(x, WQ, bQ, WK, WVw, Q, K, V);
    edge_fused_kernel<<<2048, 256, 0, stream>>>(edge_attr, WE1, bE1,
                                                sortedE, sortedSD,
                                                Q, K, V, wE, den, Num);
    finalize_kernel<<<(NN * 16 + 255) / 256, 256, 0, stream>>>(Num, den, wV);
}

// Round 10
// 392.804 us; speedup vs baseline: 1.3714x; 1.3633x over previous
//
#include <hip/hip_runtime.h>

#define NN 50000
#define NE 1600000
#define CLAMP_V 5.0f

typedef __attribute__((ext_vector_type(4))) short bf16x4;
typedef __attribute__((ext_vector_type(4))) float f32x4;

static __device__ __forceinline__ short f2bf(float x) {
    unsigned u = __builtin_bit_cast(unsigned, x);
    u += 0x7FFF + ((u >> 16) & 1);   // round-to-nearest-even
    return (short)(u >> 16);
}

static __device__ __forceinline__ unsigned pack_bf16x2(float lo, float hi) {
    return ((unsigned)(unsigned short)f2bf(hi) << 16) | (unsigned short)f2bf(lo);
}

// packed bf16x2 atomic add (CDNA3+: global_atomic_pk_add_bf16)
static __device__ __forceinline__ void atomic_pk_add_bf16(unsigned* addr, unsigned data) {
    asm volatile("global_atomic_pk_add_bf16 %0, %1, off"
                 :: "v"(addr), "v"(data) : "memory");
}

__global__ __launch_bounds__(256) void proj_kernel(
    const float* __restrict__ x,
    const float* __restrict__ WQ, const float* __restrict__ bQ,
    const float* __restrict__ WK, const float* __restrict__ WVw,
    float* __restrict__ Q, float* __restrict__ K, float* __restrict__ V)
{
    __shared__ float sWQ[4096], sWK[4096], sWV[4096];
    for (int i = threadIdx.x; i < 4096; i += 256) {
        sWQ[i] = WQ[i]; sWK[i] = WK[i]; sWV[i] = WVw[i];
    }
    __syncthreads();
    const int col = threadIdx.x & 63;
    const int nl  = threadIdx.x >> 6;
    const float bq = bQ[col];
    for (int node = blockIdx.x * 4 + nl; node < NN; node += gridDim.x * 4) {
        const float* xr = x + (size_t)node * 64;
        float aq = 0.f, ak = 0.f, av = 0.f;
        #pragma unroll
        for (int j = 0; j < 64; ++j) {
            float xv = xr[j];
            aq = fmaf(xv, sWQ[j*64+col], aq);
            ak = fmaf(xv, sWK[j*64+col], ak);
            av = fmaf(xv, sWV[j*64+col], av);
        }
        Q[(size_t)node*64+col] = aq + bq;
        K[(size_t)node*64+col] = ak;
        V[(size_t)node*64+col] = av;
    }
}

// Fused edge pass. E = edge_attr@WE1+bE1 (MFMA), sc = K[src]*Q[dst]*E -> wE,
// ex = exp(clamp(sum_head/sqrt8)); den[dst,h] += ex (f32 atomic);
// NumH[dst,:] += ex*(V[src]+sc) as packed-bf16x2 atomics —
// one instruction covers TWO edges (halves the dword-RMW count).
__global__ __launch_bounds__(256) void edge_fused_kernel(
    const float* __restrict__ edge_attr,
    const float* __restrict__ WE1, const float* __restrict__ bE1,
    const int* __restrict__ ei,
    const float* __restrict__ Q, const float* __restrict__ K,
    const float* __restrict__ V,
    float* __restrict__ wE, float* __restrict__ den, unsigned* __restrict__ NumH)
{
    __shared__ float Elds[4][16 * 64];   // [wave][edge][col]: E tile, then P in-place
    const int tid  = threadIdx.x;
    const int wv   = tid >> 6;
    const int lane = tid & 63;
    const int g    = lane >> 4;      // k-group (MFMA) / edge-in-quad (scoring)
    const int rowl = lane & 15;      // A-row (MFMA) / col-quad (scoring)

    // B fragments of WE1 (bf16) + bias. B[k=(ks*16 + g*4 + j)][col]
    bf16x4 bF[4][4];
    float  bias[4];
    #pragma unroll
    for (int cb = 0; cb < 4; ++cb) {
        const int col = rowl + 16 * cb;
        bias[cb] = bE1[col];
        #pragma unroll
        for (int ks = 0; ks < 4; ++ks) {
            bf16x4 t;
            #pragma unroll
            for (int j = 0; j < 4; ++j)
                t[j] = f2bf(WE1[(ks * 16 + g * 4 + j) * 64 + col]);
            bF[cb][ks] = t;
        }
    }

    const float inv_sqrt8 = 0.35355339059327373f;

    for (int tile = blockIdx.x; tile < (NE / 64); tile += gridDim.x) {
        const int eBase = tile * 64 + wv * 16;

        const int srcv = ei[eBase + rowl];
        const int dstv = ei[NE + eBase + rowl];

        // A fragments: edge_attr[eBase+rowl][ks*16 + g*4 + j] (nontemporal)
        bf16x4 aF[4];
        const float* ar = edge_attr + (size_t)(eBase + rowl) * 64 + g * 4;
        #pragma unroll
        for (int ks = 0; ks < 4; ++ks) {
            f32x4 v = __builtin_nontemporal_load(
                reinterpret_cast<const f32x4*>(ar + ks * 16));
            bf16x4 t;
            #pragma unroll
            for (int j = 0; j < 4; ++j) t[j] = f2bf(v[j]);
            aF[ks] = t;
        }

        f32x4 acc[4];
        #pragma unroll
        for (int cb = 0; cb < 4; ++cb) {
            acc[cb][0] = bias[cb]; acc[cb][1] = bias[cb];
            acc[cb][2] = bias[cb]; acc[cb][3] = bias[cb];
        }
        #pragma unroll
        for (int cb = 0; cb < 4; ++cb)
            #pragma unroll
            for (int ks = 0; ks < 4; ++ks)
                acc[cb] = __builtin_amdgcn_mfma_f32_16x16x16bf16_1k(
                    aF[ks], bF[cb][ks], acc[cb], 0, 0, 0);

        // D layout: row=(lane>>4)*4+r, col=(lane&15)+16*cb  -> LDS transpose
        #pragma unroll
        for (int cb = 0; cb < 4; ++cb)
            #pragma unroll
            for (int r = 0; r < 4; ++r)
                Elds[wv][(g * 4 + r) * 64 + rowl + 16 * cb] = acc[cb][r];

        // Scoring: 4 edges in parallel, float4 per lane; P overwrites E in LDS
        const int h = rowl >> 1;
        #pragma unroll
        for (int qi = 0; qi < 4; ++qi) {
            const int el  = qi * 4 + g;
            const int e   = eBase + el;
            const int src = __shfl(srcv, el);
            const int dst = __shfl(dstv, el);
            const f32x4 Kv = *reinterpret_cast<const f32x4*>(K + (size_t)src * 64 + rowl * 4);
            const f32x4 Qv = *reinterpret_cast<const f32x4*>(Q + (size_t)dst * 64 + rowl * 4);
            const f32x4 Vv = *reinterpret_cast<const f32x4*>(V + (size_t)src * 64 + rowl * 4);
            f32x4* eslot = reinterpret_cast<f32x4*>(&Elds[wv][el * 64 + rowl * 4]);
            const f32x4 El = *eslot;
            f32x4 sc;
            #pragma unroll
            for (int j = 0; j < 4; ++j) sc[j] = Kv[j] * Qv[j] * El[j];
            __builtin_nontemporal_store(sc,
                reinterpret_cast<f32x4*>(wE + (size_t)e * 64 + rowl * 4));
            float ss = sc[0] + sc[1] + sc[2] + sc[3];
            ss += __shfl_xor(ss, 1);
            float s = fminf(fmaxf(ss * inv_sqrt8, -CLAMP_V), CLAMP_V);
            float ex = __expf(s);
            if ((rowl & 1) == 0)
                atomicAdd(&den[dst * 8 + h], ex);
            f32x4 t;
            #pragma unroll
            for (int j = 0; j < 4; ++j) t[j] = ex * (Vv[j] + sc[j]);
            *eslot = t;
        }

        // Atomic phase: packed bf16x2, TWO edges per instruction
        // lanes 0-31 -> edge el2, lanes 32-63 -> edge el2+1; c2 = column pair
        const int c2 = lane & 31;
        #pragma unroll
        for (int el2 = 0; el2 < 16; el2 += 2) {
            const int el  = el2 + (lane >> 5);
            const int dst = __shfl(dstv, el);
            const float a = Elds[wv][el * 64 + c2 * 2];
            const float b = Elds[wv][el * 64 + c2 * 2 + 1];
            atomic_pk_add_bf16(NumH + (size_t)dst * 32 + c2, pack_bf16x2(a, b));
        }
    }
}

__global__ __launch_bounds__(256) void finalize_kernel(
    const unsigned* __restrict__ NumH, const float* __restrict__ den,
    float* __restrict__ wV)
{
    const int i = blockIdx.x * 256 + threadIdx.x;   // one f32x4 output per thread
    if (i >= NN * 16) return;
    const int c4 = i & 15;            // which 4-col group
    const int n  = i >> 4;
    const int h  = c4 >> 1;
    const float d = den[n * 8 + h] + 1e-16f;
    const unsigned u0 = NumH[(size_t)n * 32 + c4 * 2];
    const unsigned u1 = NumH[(size_t)n * 32 + c4 * 2 + 1];
    f32x4 v;
    v[0] = __builtin_bit_cast(float, u0 << 16);
    v[1] = __builtin_bit_cast(float, u0 & 0xffff0000u);
    v[2] = __builtin_bit_cast(float, u1 << 16);
    v[3] = __builtin_bit_cast(float, u1 & 0xffff0000u);
    v[0] /= d; v[1] /= d; v[2] /= d; v[3] /= d;
    reinterpret_cast<f32x4*>(wV)[i] = v;
}

extern "C" void kernel_launch(void* const* d_in, const int* in_sizes, int n_in,
                              void* d_out, int out_size, void* d_ws, size_t ws_size,
                              hipStream_t stream) {
    const float* x         = (const float*)d_in[0];
    const float* edge_attr = (const float*)d_in[1];
    const float* WQ        = (const float*)d_in[2];
    const float* bQ        = (const float*)d_in[3];
    const float* WK        = (const float*)d_in[4];
    const float* WVw       = (const float*)d_in[5];
    const float* WE1       = (const float*)d_in[6];
    const float* bE1       = (const float*)d_in[7];
    const int*   ei        = (const int*)d_in[8];

    float* out = (float*)d_out;
    float* wV = out;                          // [NN, 64]
    float* wE = out + (size_t)NN * 64;        // [NE, 64]

    float*    Q    = (float*)d_ws;                 // [NN,64]
    float*    K    = Q + (size_t)NN * 64;          // [NN,64]
    float*    V    = K + (size_t)NN * 64;          // [NN,64]
    float*    den  = V + (size_t)NN * 64;          // [NN,8]
    unsigned* NumH = (unsigned*)(den + (size_t)NN * 8);   // [NN,32] bf16x2

    hipMemsetAsync(den,  0, (size_t)NN * 8  * sizeof(float), stream);
    hipMemsetAsync(NumH, 0, (size_t)NN * 32 * sizeof(unsigned), stream);

    proj_kernel<<<2048, 256, 0, stream>>>(x, WQ, bQ, WK, WVw, Q, K, V);
    edge_fused_kernel<<<2048, 256, 0, stream>>>(edge_attr, WE1, bE1, ei, Q, K, V,
                                                wE, den, NumH);
    finalize_kernel<<<(NN * 16 + 255) / 256, 256, 0, stream>>>(NumH, den, wV);
}